// Round 9
// baseline (283.015 us; speedup 1.0000x reference)
//
#include <hip/hip_runtime.h>
#include <hip/hip_bf16.h>
#include <float.h>

#define BB 8
#define DD 384
#define NQ 2048
#define NK 2048
#define NEG 0.2f

typedef __attribute__((ext_vector_type(8))) __bf16 bf16x8v;
typedef __attribute__((ext_vector_type(4))) float  float4v;

__device__ __forceinline__ unsigned short bf16_rne(float x) {
  unsigned int u = __float_as_uint(x);
  return (unsigned short)((u + 0x7FFFu + ((u >> 16) & 1u)) >> 16);
}
__device__ __forceinline__ float bf16_to_f32(unsigned short h) {
  return __uint_as_float(((unsigned int)h) << 16);
}

// ================= Pre-pass 0: key pack (x,y,z,|k|^2) =================
__global__ __launch_bounds__(256) void kpack_kernel(
    const float* __restrict__ kc, float4* __restrict__ kpk)
{
  const int b = blockIdx.y;
  const int i = blockIdx.x * 256 + threadIdx.x;
  const float* kcb = kc + (size_t)b * 3 * NK;
  float x = kcb[i], y = kcb[NK + i], z = kcb[2 * NK + i];
  kpk[(size_t)b * NK + i] = make_float4(x, y, z, (x * x + y * y) + z * z);
}

// ============================ KNN (wave-cooperative, no LDS) ============================
// One wave per query; keys read straight from the packed L2-resident buffer
// (32 KB/batch), lane l takes keys {j*64+l} -> coalesced 1KB/instr.
// Extraction: per-lane TREE argmin (depth 5, contiguous pairing keeps
// lower-index-wins tie order) -> 6-step shfl_xor lexicographic (dist,key)
// min -> winner slot masked to +INF. Tie semantics == jax top_k.
// (Round-8 post-mortem: linear 31-step argmin chain + LDS staging + QPW=4
//  ran 86 us at 50% VALU / 21% occ; this cuts dep depth 31->5 and lifts
//  the grid 1024->4096 blocks.)
__global__ __launch_bounds__(256) void knn_kernel(
    const float* __restrict__ qc, const float4* __restrict__ kpk,
    int* __restrict__ idx)
{
  const int t = threadIdx.x;
  const int b = blockIdx.y;
  const int w = t >> 6, l = t & 63;
  const int q = blockIdx.x * 4 + w;

  const float* qcb = qc + (size_t)b * 3 * NQ;
  const float qx = qcb[q], qy = qcb[NQ + q], qz = qcb[2 * NQ + q];
  const float q2 = (qx * qx + qy * qy) + qz * qz;

  const float4* kb = kpk + (size_t)b * NK;
  float d[32];
  #pragma unroll
  for (int j = 0; j < 32; ++j) {
    float4 kv = kb[j * 64 + l];
    float inner = (qx * kv.x + qy * kv.y) + qz * kv.z;
    d[j] = (q2 - 2.0f * inner) + kv.w;
  }

  int outk[8];
  #pragma unroll
  for (int r = 0; r < 8; ++r) {
    // tree argmin over 32 regs: work = linear scan, dep depth 5 not 31.
    // right wins only on strict '<' => lower slot index (lower key) on ties.
    float v16[16]; int i16[16];
    #pragma unroll
    for (int i = 0; i < 16; ++i) {
      bool c = d[2 * i + 1] < d[2 * i];
      v16[i] = c ? d[2 * i + 1] : d[2 * i];
      i16[i] = c ? 2 * i + 1 : 2 * i;
    }
    float v8[8]; int i8[8];
    #pragma unroll
    for (int i = 0; i < 8; ++i) {
      bool c = v16[2 * i + 1] < v16[2 * i];
      v8[i] = c ? v16[2 * i + 1] : v16[2 * i];
      i8[i] = c ? i16[2 * i + 1] : i16[2 * i];
    }
    float v4[4]; int i4[4];
    #pragma unroll
    for (int i = 0; i < 4; ++i) {
      bool c = v8[2 * i + 1] < v8[2 * i];
      v4[i] = c ? v8[2 * i + 1] : v8[2 * i];
      i4[i] = c ? i8[2 * i + 1] : i8[2 * i];
    }
    float v2[2]; int i2[2];
    #pragma unroll
    for (int i = 0; i < 2; ++i) {
      bool c = v4[2 * i + 1] < v4[2 * i];
      v2[i] = c ? v4[2 * i + 1] : v4[2 * i];
      i2[i] = c ? i4[2 * i + 1] : i4[2 * i];
    }
    bool c0 = v2[1] < v2[0];
    float m = c0 ? v2[1] : v2[0];
    int  mj = c0 ? i2[1] : i2[0];

    int mkey = mj * 64 + l;
    #pragma unroll
    for (int off = 32; off >= 1; off >>= 1) {
      float om = __shfl_xor(m, off);
      int   ok = __shfl_xor(mkey, off);
      bool take = (om < m) || (om == m && ok < mkey);
      m    = take ? om : m;
      mkey = take ? ok : mkey;
    }
    outk[r] = mkey;
    const bool mine = (l == (mkey & 63));
    const int  slot = mkey >> 6;
    #pragma unroll
    for (int j = 0; j < 32; ++j) {
      bool kill = mine && (j == slot);
      d[j] = kill ? FLT_MAX : d[j];
    }
  }

  int myv = outk[0];
  #pragma unroll
  for (int r = 1; r < 8; ++r) myv = (l == r) ? outk[r] : myv;
  if (l < 8) idx[((size_t)b * NQ + q) * 8 + l] = myv;
}

// ================= Pre-pass 1: feats transpose + bf16 hi/lo split =================
__global__ __launch_bounds__(256) void transpose_pack_kernel(
    const float* __restrict__ kf, const float* __restrict__ qf,
    unsigned short* __restrict__ Apk)
{
  __shared__ float tile[64][68];
  const int t = threadIdx.x;
  const int z = blockIdx.z;
  const int b = z & 7;
  const float* src = ((z >> 3) ? qf : kf) + (size_t)b * DD * 2048;
  const int f0 = blockIdx.y * 64;
  const int n0 = blockIdx.x * 64;

  {
    const int fr = t >> 2, nc = (t & 3) * 16;
    const float* p = src + (size_t)(f0 + fr) * 2048 + n0 + nc;
    float4 v0 = *(const float4*)(p);
    float4 v1 = *(const float4*)(p + 4);
    float4 v2 = *(const float4*)(p + 8);
    float4 v3 = *(const float4*)(p + 12);
    *(float4*)&tile[fr][nc]      = v0;
    *(float4*)&tile[fr][nc + 4]  = v1;
    *(float4*)&tile[fr][nc + 8]  = v2;
    *(float4*)&tile[fr][nc + 12] = v3;
  }
  __syncthreads();
  {
    const int nr = t >> 2, fc = (t & 3) * 16;
    unsigned int hp[8], lp[8];
    #pragma unroll
    for (int i = 0; i < 8; ++i) {
      float va = tile[fc + 2 * i][nr];
      float vb = tile[fc + 2 * i + 1][nr];
      unsigned short ha = bf16_rne(va), hb = bf16_rne(vb);
      unsigned short la = bf16_rne(va - bf16_to_f32(ha));
      unsigned short lb = bf16_rne(vb - bf16_to_f32(hb));
      hp[i] = (unsigned int)ha | ((unsigned int)hb << 16);
      lp[i] = (unsigned int)la | ((unsigned int)lb << 16);
    }
    unsigned short* row = Apk + ((size_t)z * 2048 + n0 + nr) * (2 * DD);
    *(uint4*)(row + f0 + fc)          = make_uint4(hp[0], hp[1], hp[2], hp[3]);
    *(uint4*)(row + f0 + fc + 8)      = make_uint4(hp[4], hp[5], hp[6], hp[7]);
    *(uint4*)(row + DD + f0 + fc)     = make_uint4(lp[0], lp[1], lp[2], lp[3]);
    *(uint4*)(row + DD + f0 + fc + 8) = make_uint4(lp[4], lp[5], lp[6], lp[7]);
  }
}

// ================= Pre-pass 2: W pack =================
__global__ __launch_bounds__(192) void wpack_kernel(
    const float* __restrict__ W, unsigned short* __restrict__ Wpk)
{
  const int d = blockIdx.x;
  const int mode = blockIdx.y;
  const int t = threadIdx.x;
  const float* wrow = W + (size_t)d * (2 * DD) + t * 2;
  float2 w1 = *(const float2*)(wrow);
  float a = w1.x, c = w1.y;
  if (mode) {
    float2 w2 = *(const float2*)(wrow + DD);
    a = w2.x - a; c = w2.y - c;
  }
  unsigned short ha = bf16_rne(a), hc = bf16_rne(c);
  unsigned short la = bf16_rne(a - bf16_to_f32(ha));
  unsigned short lc = bf16_rne(c - bf16_to_f32(hc));
  unsigned short* orow = Wpk + ((size_t)mode * DD + d) * (2 * DD);
  *(unsigned int*)(orow + t * 2)      = (unsigned int)ha | ((unsigned int)hc << 16);
  *(unsigned int*)(orow + DD + t * 2) = (unsigned int)la | ((unsigned int)lc << 16);
}

// ================= MFMA GEMM (bf16x3 split: hi*hi + hi*lo + lo*hi) =================
__global__ __launch_bounds__(256) void proj_gemm_mfma(
    const unsigned short* __restrict__ Apk,  // [16][2048][2*DD]
    const unsigned short* __restrict__ Wpk,  // [2][DD][2*DD]
    const float* __restrict__ bias,
    float* __restrict__ pk, float* __restrict__ pq)
{
  __shared__ unsigned short Alds[128][72];
  __shared__ unsigned short Blds[128][72];

  const int t = threadIdx.x;
  const int z = blockIdx.z, b = z & 7, mode = z >> 3;
  const int n0 = blockIdx.x * 128;
  const int d0 = blockIdx.y * 128;
  const int w = t >> 6, l = t & 63;
  const int wn = w & 1, wd = w >> 1;
  const int lr = l & 15, g = l >> 4;

  float4v acc[4][4];
  #pragma unroll
  for (int i = 0; i < 4; ++i)
    #pragma unroll
    for (int j = 0; j < 4; ++j) acc[i][j] = (float4v){0.f, 0.f, 0.f, 0.f};

  const int sr = t >> 1, sh = (t & 1) * 32;
  const unsigned short* asrc = Apk + ((size_t)z * 2048 + n0 + sr) * (2 * DD) + (t & 1) * DD;
  const unsigned short* bsrc = Wpk + ((size_t)mode * DD + d0 + sr) * (2 * DD) + (t & 1) * DD;

  for (int ks = 0; ks < 12; ++ks) {
    const int kt = ks * 32;
    float4 a0 = *(const float4*)(asrc + kt);
    float4 a1 = *(const float4*)(asrc + kt + 8);
    float4 a2 = *(const float4*)(asrc + kt + 16);
    float4 a3 = *(const float4*)(asrc + kt + 24);
    float4 b0 = *(const float4*)(bsrc + kt);
    float4 b1 = *(const float4*)(bsrc + kt + 8);
    float4 b2 = *(const float4*)(bsrc + kt + 16);
    float4 b3 = *(const float4*)(bsrc + kt + 24);
    __syncthreads();
    *(float4*)&Alds[sr][sh]      = a0;
    *(float4*)&Alds[sr][sh + 8]  = a1;
    *(float4*)&Alds[sr][sh + 16] = a2;
    *(float4*)&Alds[sr][sh + 24] = a3;
    *(float4*)&Blds[sr][sh]      = b0;
    *(float4*)&Blds[sr][sh + 8]  = b1;
    *(float4*)&Blds[sr][sh + 16] = b2;
    *(float4*)&Blds[sr][sh + 24] = b3;
    __syncthreads();

    bf16x8v ah[4], al[4], bh[4], bl[4];
    #pragma unroll
    for (int i = 0; i < 4; ++i) {
      ah[i] = *(const bf16x8v*)&Alds[wn * 64 + i * 16 + lr][g * 8];
      al[i] = *(const bf16x8v*)&Alds[wn * 64 + i * 16 + lr][32 + g * 8];
      bh[i] = *(const bf16x8v*)&Blds[wd * 64 + i * 16 + lr][g * 8];
      bl[i] = *(const bf16x8v*)&Blds[wd * 64 + i * 16 + lr][32 + g * 8];
    }
    #pragma unroll
    for (int i = 0; i < 4; ++i)
      #pragma unroll
      for (int j = 0; j < 4; ++j) {
        acc[i][j] = __builtin_amdgcn_mfma_f32_16x16x32_bf16(ah[i], bh[j], acc[i][j], 0, 0, 0);
        acc[i][j] = __builtin_amdgcn_mfma_f32_16x16x32_bf16(ah[i], bl[j], acc[i][j], 0, 0, 0);
        acc[i][j] = __builtin_amdgcn_mfma_f32_16x16x32_bf16(al[i], bh[j], acc[i][j], 0, 0, 0);
      }
  }

  float bv[4];
  #pragma unroll
  for (int j = 0; j < 4; ++j)
    bv[j] = mode ? bias[d0 + wd * 64 + j * 16 + lr] : 0.f;

  float* out = (mode ? pq : pk) + (size_t)b * 2048 * DD;
  #pragma unroll
  for (int i = 0; i < 4; ++i) {
    const int nb_ = n0 + wn * 64 + i * 16 + g * 4;
    #pragma unroll
    for (int j = 0; j < 4; ++j) {
      const int dcol = d0 + wd * 64 + j * 16 + lr;
      #pragma unroll
      for (int r = 0; r < 4; ++r)
        out[(size_t)(nb_ + r) * DD + dcol] = acc[i][j][r] + bv[j];
    }
  }
}

// ===================== Fallback f32 GEMM (round-7-verified) =====================
__global__ __launch_bounds__(256) void proj_gemm_all(
    const float* __restrict__ kf, const float* __restrict__ qf,
    const float* __restrict__ W, const float* __restrict__ bias,
    float* __restrict__ pk, float* __restrict__ pq)
{
  __shared__ float At[16][128];
  __shared__ float Bt[16][132];
  const int t = threadIdx.x;
  const int z = blockIdx.z, b = z & 7, mode = z >> 3;
  const int n0 = blockIdx.x * 128, d0 = blockIdx.y * 128;
  const int td = t & 15, tn = t >> 4;
  float acc[8][8];
  #pragma unroll
  for (int i = 0; i < 8; ++i)
    #pragma unroll
    for (int j = 0; j < 8; ++j) acc[i][j] = 0.f;
  const float* feats = mode ? qf : kf;
  float* out = mode ? pq : pk;
  const float* fb = feats + (size_t)b * DD * 2048;
  const int ar = t >> 5, ac = (t & 31) * 4, bdl = t >> 2, bf = (t & 3) * 4;
  float4 sa0, sa1, sw1a, sw1b, sw2a, sw2b;
#define PREFETCH(KT)                                                           \
  {                                                                            \
    sa0 = *(const float4*)&fb[(size_t)((KT) + ar) * 2048 + n0 + ac];           \
    sa1 = *(const float4*)&fb[(size_t)((KT) + ar + 8) * 2048 + n0 + ac];       \
    const float* wr0 = W + (size_t)(d0 + bdl) * (2 * DD) + (KT) + bf;          \
    const float* wr1 = W + (size_t)(d0 + bdl + 64) * (2 * DD) + (KT) + bf;     \
    sw1a = *(const float4*)wr0; sw1b = *(const float4*)wr1;                    \
    if (mode) { sw2a = *(const float4*)(wr0 + DD); sw2b = *(const float4*)(wr1 + DD); } \
  }
  PREFETCH(0);
  for (int kt = 0; kt < DD; kt += 16) {
    *(float4*)&At[ar][ac]     = sa0;
    *(float4*)&At[ar + 8][ac] = sa1;
    {
      float4 w = sw1a;
      if (mode) { w.x = sw2a.x - w.x; w.y = sw2a.y - w.y; w.z = sw2a.z - w.z; w.w = sw2a.w - w.w; }
      Bt[bf + 0][bdl] = w.x; Bt[bf + 1][bdl] = w.y; Bt[bf + 2][bdl] = w.z; Bt[bf + 3][bdl] = w.w;
    }
    {
      float4 w = sw1b;
      if (mode) { w.x = sw2b.x - w.x; w.y = sw2b.y - w.y; w.z = sw2b.z - w.z; w.w = sw2b.w - w.w; }
      Bt[bf + 0][bdl + 64] = w.x; Bt[bf + 1][bdl + 64] = w.y; Bt[bf + 2][bdl + 64] = w.z; Bt[bf + 3][bdl + 64] = w.w;
    }
    __syncthreads();
    if (kt + 16 < DD) PREFETCH(kt + 16);
    #pragma unroll
    for (int k = 0; k < 16; ++k) {
      float a[8], bb[8];
      {
        float4 v = *(const float4*)&At[k][tn * 4];
        a[0] = v.x; a[1] = v.y; a[2] = v.z; a[3] = v.w;
        v = *(const float4*)&At[k][tn * 4 + 64];
        a[4] = v.x; a[5] = v.y; a[6] = v.z; a[7] = v.w;
        v = *(const float4*)&Bt[k][td * 4];
        bb[0] = v.x; bb[1] = v.y; bb[2] = v.z; bb[3] = v.w;
        v = *(const float4*)&Bt[k][td * 4 + 64];
        bb[4] = v.x; bb[5] = v.y; bb[6] = v.z; bb[7] = v.w;
      }
      #pragma unroll
      for (int i = 0; i < 8; ++i)
        #pragma unroll
        for (int j = 0; j < 8; ++j)
          acc[i][j] = fmaf(a[i], bb[j], acc[i][j]);
    }
    __syncthreads();
  }
#undef PREFETCH
  float4 blo = make_float4(0.f, 0.f, 0.f, 0.f);
  float4 bhi = make_float4(0.f, 0.f, 0.f, 0.f);
  if (mode) {
    blo = *(const float4*)&bias[d0 + td * 4];
    bhi = *(const float4*)&bias[d0 + td * 4 + 64];
  }
  float* ob = out + (size_t)b * 2048 * DD;
  #pragma unroll
  for (int i = 0; i < 8; ++i) {
    int n = n0 + tn * 4 + (i & 3) + ((i >= 4) ? 64 : 0);
    float4 c0, c1;
    c0.x = acc[i][0] + blo.x; c0.y = acc[i][1] + blo.y;
    c0.z = acc[i][2] + blo.z; c0.w = acc[i][3] + blo.w;
    c1.x = acc[i][4] + bhi.x; c1.y = acc[i][5] + bhi.y;
    c1.z = acc[i][6] + bhi.z; c1.w = acc[i][7] + bhi.w;
    *(float4*)&ob[(size_t)n * DD + d0 + td * 4]      = c0;
    *(float4*)&ob[(size_t)n * DD + d0 + td * 4 + 64] = c1;
  }
}

// ============== Gather + max over 8 neighbors + LeakyReLU ==============
__global__ __launch_bounds__(384) void gather_max_kernel(
    const float4* __restrict__ pk4, const float4* pq4,
    const int* __restrict__ idx, float4* out4)
{
  const int t = threadIdx.x;
  const int bq0 = blockIdx.x * 4;
  __shared__ int nb[4][8];
  if (t < 32) nb[t >> 3][t & 7] = idx[(size_t)(bq0 + (t >> 3)) * 8 + (t & 7)];
  __syncthreads();
  const int q_l = t / 96;
  const int dv  = t - q_l * 96;
  const int bq  = bq0 + q_l;
  const int b   = bq >> 11;
  const float4* pkb = pk4 + (size_t)b * NK * 96;
  float4 m = make_float4(-FLT_MAX, -FLT_MAX, -FLT_MAX, -FLT_MAX);
  #pragma unroll
  for (int s = 0; s < 8; ++s) {
    float4 v = pkb[(size_t)nb[q_l][s] * 96 + dv];
    m.x = fmaxf(m.x, v.x); m.y = fmaxf(m.y, v.y);
    m.z = fmaxf(m.z, v.z); m.w = fmaxf(m.w, v.w);
  }
  float4 c = pq4[(size_t)bq * 96 + dv];
  float4 r;
  r.x = m.x + c.x; r.y = m.y + c.y; r.z = m.z + c.z; r.w = m.w + c.w;
  r.x = (r.x >= 0.f) ? r.x : NEG * r.x;
  r.y = (r.y >= 0.f) ? r.y : NEG * r.y;
  r.z = (r.z >= 0.f) ? r.z : NEG * r.z;
  r.w = (r.w >= 0.f) ? r.w : NEG * r.w;
  out4[(size_t)bq * 96 + dv] = r;
}

extern "C" void kernel_launch(void* const* d_in, const int* in_sizes, int n_in,
                              void* d_out, int out_size, void* d_ws, size_t ws_size,
                              hipStream_t stream) {
  const float* qc   = (const float*)d_in[0];
  const float* qf   = (const float*)d_in[1];
  const float* kc   = (const float*)d_in[2];
  const float* kf   = (const float*)d_in[3];
  const float* W    = (const float*)d_in[4];
  const float* bias = (const float*)d_in[5];
  float* out = (float*)d_out;
  char* ws = (char*)d_ws;

  const size_t APK_BYTES = (size_t)16 * 2048 * (2 * DD) * 2;  // 50,331,648
  const size_t WPK_BYTES = (size_t)2 * DD * (2 * DD) * 2;     //  1,179,648
  const size_t PK_BYTES  = (size_t)BB * NK * DD * 4;          // 25,165,824
  const size_t IDX_BYTES = (size_t)BB * NQ * 8 * 4;           //     524,288

  if (ws_size >= APK_BYTES + WPK_BYTES + PK_BYTES + IDX_BYTES) {
    unsigned short* Apk = (unsigned short*)ws;
    unsigned short* Wpk = (unsigned short*)(ws + APK_BYTES);
    float* pk = (float*)(ws + APK_BYTES + WPK_BYTES);
    int*   ix = (int*)  (ws + APK_BYTES + WPK_BYTES + PK_BYTES);
    float* pq = out;          // d_out doubles as PQ
    float4* kpk = (float4*)pk; // kpk aliases pk: knn consumes it BEFORE gemm writes pk

    kpack_kernel<<<dim3(NK / 256, BB), 256, 0, stream>>>(kc, kpk);
    knn_kernel<<<dim3(NQ / 4, BB), 256, 0, stream>>>(qc, kpk, ix);
    transpose_pack_kernel<<<dim3(32, 6, 16), 256, 0, stream>>>(kf, qf, Apk);
    wpack_kernel<<<dim3(DD, 2), 192, 0, stream>>>(W, Wpk);
    proj_gemm_mfma<<<dim3(16, 3, 16), 256, 0, stream>>>(Apk, Wpk, bias, pk, pq);
    gather_max_kernel<<<dim3(BB * NQ / 4), 384, 0, stream>>>(
        (const float4*)pk, (const float4*)pq, ix, (float4*)out);
  } else {
    float* pk = (float*)ws;
    float* pq = (float*)(ws + PK_BYTES);
    int*   ix = (int*)  (ws + 2 * PK_BYTES);
    float4* kpk = (float4*)pk;

    kpack_kernel<<<dim3(NK / 256, BB), 256, 0, stream>>>(kc, kpk);
    knn_kernel<<<dim3(NQ / 4, BB), 256, 0, stream>>>(qc, kpk, ix);
    proj_gemm_all<<<dim3(16, 3, 16), 256, 0, stream>>>(kf, qf, W, bias, pk, pq);
    gather_max_kernel<<<dim3(BB * NQ / 4), 384, 0, stream>>>(
        (const float4*)pk, (const float4*)pq, ix, (float4*)out);
  }
}